// Round 5
// baseline (2337.443 us; speedup 1.0000x reference)
//
#include <hip/hip_runtime.h>

// ---- problem dims ----
#define Bn   8192
#define In   1024
#define Hn   1024
#define Dn   2048   // 2*H
#define NHn  16
#define HDn  128
#define Cn   7

using u16 = unsigned short;

typedef __bf16 bf16x8 __attribute__((ext_vector_type(8)));
typedef float  f32x4  __attribute__((ext_vector_type(4)));

__device__ __forceinline__ float bf2f(u16 h) {
    union { unsigned u; float f; } v; v.u = ((unsigned)h) << 16; return v.f;
}
__device__ __forceinline__ u16 f2bf(float f) {
    union { float f; unsigned u; } v; v.f = f;
    unsigned r = v.u + 0x7FFFu + ((v.u >> 16) & 1u);   // RNE
    return (u16)(r >> 16);
}

// ---------------- f32 -> bf16 conversion (vector x4) ----------------
__global__ void cvt_f32_bf16(const float* __restrict__ in, u16* __restrict__ out, long n4) {
    long i = (long)blockIdx.x * blockDim.x + threadIdx.x;
    if (i >= n4) return;
    float4 v = reinterpret_cast<const float4*>(in)[i];
    ushort4 o;
    o.x = f2bf(v.x); o.y = f2bf(v.y); o.z = f2bf(v.z); o.w = f2bf(v.w);
    reinterpret_cast<ushort4*>(out)[i] = o;
}

// ---------------- generic NT bf16 GEMM: C[M,N] = A[M,K] * W[N,K]^T ----------------
// 128x128 tile, BK=64, 256 threads (4 waves, 2x2 of 64x64), mfma 16x16x32 bf16.
// M%128==0, N%128==0, K%64==0 assumed (true for all shapes here).
__device__ __forceinline__ void gload_lds16(const void* g, void* l) {
    __builtin_amdgcn_global_load_lds(
        (const __attribute__((address_space(1))) void*)g,
        (__attribute__((address_space(3))) void*)l,
        16, 0, 0);
}

__global__ __launch_bounds__(256)
void gemm_bt(const u16* __restrict__ A, long lda,
             const u16* __restrict__ W, long ldb,
             u16* __restrict__ C, long ldc, int K)
{
    __shared__ u16 As[128 * 64];
    __shared__ u16 Bs[128 * 64];
    const int tid  = threadIdx.x;
    const int wave = tid >> 6, lane = tid & 63;
    const int wr = wave >> 1, wc = wave & 1;
    const int fm = lane & 15;            // fragment row (A) / col (B)
    const int fk = (lane >> 4) * 8;      // fragment k offset within 32

    const u16* Ab = A + (size_t)blockIdx.x * 128 * lda;
    const u16* Wb = W + (size_t)blockIdx.y * 128 * ldb;

    f32x4 acc[4][4];
    #pragma unroll
    for (int i = 0; i < 4; ++i)
        #pragma unroll
        for (int j = 0; j < 4; ++j)
            acc[i][j] = (f32x4){0.f, 0.f, 0.f, 0.f};

    const int lrow = lane >> 3;          // 0..7
    const int lcol = (lane & 7) * 8;     // 0..56

    for (int k0 = 0; k0 < K; k0 += 64) {
        // stage 128x64 A-tile and B-tile; 16 segments of 1KB, wave-uniform LDS base
        #pragma unroll
        for (int i = 0; i < 4; ++i) {
            int seg = wave * 4 + i;
            int row = seg * 8 + lrow;
            gload_lds16(Ab + (size_t)row * lda + k0 + lcol, (char*)As + seg * 1024);
            gload_lds16(Wb + (size_t)row * ldb + k0 + lcol, (char*)Bs + seg * 1024);
        }
        __syncthreads();

        #pragma unroll
        for (int kk = 0; kk < 64; kk += 32) {
            bf16x8 af[4], bfr[4];
            #pragma unroll
            for (int i = 0; i < 4; ++i) {
                af[i]  = *reinterpret_cast<const bf16x8*>(&As[(wr*64 + i*16 + fm)*64 + kk + fk]);
                bfr[i] = *reinterpret_cast<const bf16x8*>(&Bs[(wc*64 + i*16 + fm)*64 + kk + fk]);
            }
            #pragma unroll
            for (int mi = 0; mi < 4; ++mi)
                #pragma unroll
                for (int ni = 0; ni < 4; ++ni)
                    acc[mi][ni] = __builtin_amdgcn_mfma_f32_16x16x32_bf16(af[mi], bfr[ni], acc[mi][ni], 0, 0, 0);
        }
        __syncthreads();
    }

    // C/D layout: col = lane&15, row = (lane>>4)*4 + j   [m89/m91 verified]
    const int crow = (lane >> 4) * 4;
    const int ccol = lane & 15;
    #pragma unroll
    for (int mi = 0; mi < 4; ++mi) {
        #pragma unroll
        for (int ni = 0; ni < 4; ++ni) {
            size_t r0 = (size_t)blockIdx.x * 128 + wr*64 + mi*16 + crow;
            size_t c0 = (size_t)blockIdx.y * 128 + wc*64 + ni*16 + ccol;
            #pragma unroll
            for (int j = 0; j < 4; ++j)
                C[(r0 + j) * ldc + c0] = f2bf(acc[mi][ni][j]);
        }
    }
}

// ---------------- GRU pointwise gates ----------------
// gi: bf16 (8192,3072) row stride 3072, cols [0,1024)=r,[1024..)=z,[2048..)=n
// gh: bf16 (8192,3072) or nullptr (first step); hprev/hout inside hs (row stride 6144).
__global__ void gru_pointwise(const u16* __restrict__ gi,
                              const u16* __restrict__ gh,
                              const float* __restrict__ b_ih,
                              const float* __restrict__ b_hh,
                              const u16* __restrict__ hprev,
                              u16* __restrict__ hout)
{
    int idx = blockIdx.x * 256 + threadIdx.x;     // Bn*256 threads, 4 elems each
    int b = idx >> 8;
    int j = (idx & 255) << 2;
    const u16* gir = gi + (size_t)b * 3072;
    ushort4 gr4 = *reinterpret_cast<const ushort4*>(gir + j);
    ushort4 gz4 = *reinterpret_cast<const ushort4*>(gir + 1024 + j);
    ushort4 gn4 = *reinterpret_cast<const ushort4*>(gir + 2048 + j);
    float4 bir = *reinterpret_cast<const float4*>(b_ih + j);
    float4 biz = *reinterpret_cast<const float4*>(b_ih + 1024 + j);
    float4 bin_= *reinterpret_cast<const float4*>(b_ih + 2048 + j);
    float4 bhr = *reinterpret_cast<const float4*>(b_hh + j);
    float4 bhz = *reinterpret_cast<const float4*>(b_hh + 1024 + j);
    float4 bhn = *reinterpret_cast<const float4*>(b_hh + 2048 + j);

    float ghr[4] = {0,0,0,0}, ghz[4] = {0,0,0,0}, ghn[4] = {0,0,0,0};
    if (gh) {
        const u16* g = gh + (size_t)b * 3072;
        ushort4 a = *reinterpret_cast<const ushort4*>(g + j);
        ushort4 c = *reinterpret_cast<const ushort4*>(g + 1024 + j);
        ushort4 d = *reinterpret_cast<const ushort4*>(g + 2048 + j);
        ghr[0]=bf2f(a.x); ghr[1]=bf2f(a.y); ghr[2]=bf2f(a.z); ghr[3]=bf2f(a.w);
        ghz[0]=bf2f(c.x); ghz[1]=bf2f(c.y); ghz[2]=bf2f(c.z); ghz[3]=bf2f(c.w);
        ghn[0]=bf2f(d.x); ghn[1]=bf2f(d.y); ghn[2]=bf2f(d.z); ghn[3]=bf2f(d.w);
    }
    float hp[4] = {0,0,0,0};
    if (hprev) {
        ushort4 h4 = *reinterpret_cast<const ushort4*>(hprev + (size_t)b * 6144 + j);
        hp[0]=bf2f(h4.x); hp[1]=bf2f(h4.y); hp[2]=bf2f(h4.z); hp[3]=bf2f(h4.w);
    }
    float ir[4]  = {bf2f(gr4.x)+bir.x, bf2f(gr4.y)+bir.y, bf2f(gr4.z)+bir.z, bf2f(gr4.w)+bir.w};
    float iz[4]  = {bf2f(gz4.x)+biz.x, bf2f(gz4.y)+biz.y, bf2f(gz4.z)+biz.z, bf2f(gz4.w)+biz.w};
    float inn[4] = {bf2f(gn4.x)+bin_.x, bf2f(gn4.y)+bin_.y, bf2f(gn4.z)+bin_.z, bf2f(gn4.w)+bin_.w};
    float hrv[4] = {ghr[0]+bhr.x, ghr[1]+bhr.y, ghr[2]+bhr.z, ghr[3]+bhr.w};
    float hzv[4] = {ghz[0]+bhz.x, ghz[1]+bhz.y, ghz[2]+bhz.z, ghz[3]+bhz.w};
    float hnv[4] = {ghn[0]+bhn.x, ghn[1]+bhn.y, ghn[2]+bhn.z, ghn[3]+bhn.w};

    u16 ov[4];
    #pragma unroll
    for (int e = 0; e < 4; ++e) {
        float r = 1.f / (1.f + expf(-(ir[e] + hrv[e])));
        float z = 1.f / (1.f + expf(-(iz[e] + hzv[e])));
        float n = tanhf(inn[e] + r * hnv[e]);
        ov[e] = f2bf((1.f - z) * n + z * hp[e]);
    }
    ushort4 o; o.x=ov[0]; o.y=ov[1]; o.z=ov[2]; o.w=ov[3];
    *reinterpret_cast<ushort4*>(hout + (size_t)b * 6144 + j) = o;
}

// ---------------- tiny attention (S=3), one 2048-batch tile ----------------
// qkv: (2048*3, 6144) bf16, Q at col 0, K at 2048, V at 4096, row = b_local*3 + t.
// csum[b_local][d] = sum_t ctx[t][d] = sum_s (sum_t w[t][s]) v[s][d]  (bf16).
__global__ void attn_kernel(const u16* __restrict__ qkv, u16* __restrict__ csum)
{
    int gw = blockIdx.x * 4 + (threadIdx.x >> 6);   // wave id = (b_local, head)
    int lane = threadIdx.x & 63;
    int b = gw >> 4, head = gw & 15;                // b in [0,2048)
    const size_t rb = (size_t)b * 3 * 6144 + (size_t)head * HDn;
    float q[3][2], k[3][2], v[3][2];
    #pragma unroll
    for (int t = 0; t < 3; ++t) {
        size_t r = rb + (size_t)t * 6144;
        q[t][0] = bf2f(qkv[r + lane]);        q[t][1] = bf2f(qkv[r + 64 + lane]);
        k[t][0] = bf2f(qkv[r + 2048 + lane]); k[t][1] = bf2f(qkv[r + 2048 + 64 + lane]);
        v[t][0] = bf2f(qkv[r + 4096 + lane]); v[t][1] = bf2f(qkv[r + 4096 + 64 + lane]);
    }
    float lg[3][3];
    #pragma unroll
    for (int t = 0; t < 3; ++t)
        #pragma unroll
        for (int s = 0; s < 3; ++s) {
            float p = q[t][0]*k[s][0] + q[t][1]*k[s][1];
            p += __shfl_xor(p, 32); p += __shfl_xor(p, 16); p += __shfl_xor(p, 8);
            p += __shfl_xor(p, 4);  p += __shfl_xor(p, 2);  p += __shfl_xor(p, 1);
            lg[t][s] = p * 0.08838834764831845f;   // HD^-0.5
        }
    float wsum[3] = {0.f, 0.f, 0.f};
    #pragma unroll
    for (int t = 0; t < 3; ++t) {
        float m = fmaxf(lg[t][0], fmaxf(lg[t][1], lg[t][2]));
        float e0 = expf(lg[t][0]-m), e1 = expf(lg[t][1]-m), e2 = expf(lg[t][2]-m);
        float inv = 1.f / (e0 + e1 + e2);
        wsum[0] += e0*inv; wsum[1] += e1*inv; wsum[2] += e2*inv;
    }
    float o0 = wsum[0]*v[0][0] + wsum[1]*v[1][0] + wsum[2]*v[2][0];
    float o1 = wsum[0]*v[0][1] + wsum[1]*v[1][1] + wsum[2]*v[2][1];
    size_t ob = (size_t)b * Dn + (size_t)head * HDn;
    csum[ob + lane]      = f2bf(o0);
    csum[ob + 64 + lane] = f2bf(o1);
}

// ---------------- final classifier + softmax ----------------
__global__ void final_kernel(const u16* __restrict__ h, const float* __restrict__ Wout,
                             const float* __restrict__ bout, float* __restrict__ out)
{
    int b = blockIdx.x * 4 + (threadIdx.x >> 6);
    int lane = threadIdx.x & 63;
    const u16* hb = h + (size_t)b * Dn;
    float acc[7] = {0,0,0,0,0,0,0};
    for (int d = lane; d < Dn; d += 64) {
        float hv = bf2f(hb[d]);
        #pragma unroll
        for (int c = 0; c < 7; ++c) acc[c] += hv * Wout[c*Dn + d];
    }
    #pragma unroll
    for (int c = 0; c < 7; ++c) {
        float p = acc[c];
        p += __shfl_xor(p, 32); p += __shfl_xor(p, 16); p += __shfl_xor(p, 8);
        p += __shfl_xor(p, 4);  p += __shfl_xor(p, 2);  p += __shfl_xor(p, 1);
        acc[c] = p + bout[c];
    }
    float m = acc[0];
    #pragma unroll
    for (int c = 1; c < 7; ++c) m = fmaxf(m, acc[c]);
    float e[7], s = 0.f;
    #pragma unroll
    for (int c = 0; c < 7; ++c) { e[c] = expf(acc[c] - m); s += e[c]; }
    float inv = 1.f / s;
    if (lane < 7) {
        out[(size_t)b * Cn + lane] = acc[lane];
        out[(size_t)Bn * Cn + (size_t)b * Cn + lane] = e[lane] * inv;
    }
}

// ---------------- launch ----------------
// ws layout (bytes), PEAK = 260,046,848 (~248 MiB):
//   [0, 100663296)           hs   (8192, 3, 2048) bf16         [GRU..QKV]
//   [100663296, 134217728)   csum (8192, 2048) bf16            [attn..Wo]
//   [134217728, 159383552)   W region (25,165,824):
//        phase A: WihF | WihB | WhhF | WhhB  (4 x 6,291,456)
//        phase B: Wqkv (6144,2048) bf16
//        phase C: WoB  (2048,2048) bf16
//   [159383552, 260046848)   scratch:
//        phase A: gi (8192,3072) bf16 @ +0 ; xb/gh shared @ +50331648
//        phase B: qkv tile (6144,6144) bf16 @ +0
//        phase C: hWo (8192,2048) bf16 @ +0
#define WS_NEEDED 260046848ULL
extern "C" void kernel_launch(void* const* d_in, const int* in_sizes, int n_in,
                              void* d_out, int out_size, void* d_ws, size_t ws_size,
                              hipStream_t stream)
{
    // Diagnostic guard: if the harness workspace is smaller than this layout
    // needs, skip all launches (deterministic w.r.t. every call — graph-safe).
    // A clean absmax failure (vs a memory-fault abort) then confirms ws_size
    // as the R2 crash cause.
    if (ws_size < WS_NEEDED) return;

    const float* xs[3] = { (const float*)d_in[0], (const float*)d_in[1], (const float*)d_in[2] };
    const float* Wihf = (const float*)d_in[3];
    const float* Whhf = (const float*)d_in[4];
    const float* bihf = (const float*)d_in[5];
    const float* bhhf = (const float*)d_in[6];
    const float* Wihb = (const float*)d_in[7];
    const float* Whhb = (const float*)d_in[8];
    const float* bihb = (const float*)d_in[9];
    const float* bhhb = (const float*)d_in[10];
    const float* Wq   = (const float*)d_in[11];
    const float* Wk   = (const float*)d_in[12];
    const float* Wv   = (const float*)d_in[13];
    const float* Wo   = (const float*)d_in[14];
    const float* Wout = (const float*)d_in[15];
    const float* bout = (const float*)d_in[16];
    float* out = (float*)d_out;

    char* ws = (char*)d_ws;
    u16* hs   = (u16*)(ws + 0);
    u16* csum = (u16*)(ws + 100663296);
    u16* WihF = (u16*)(ws + 134217728);
    u16* WihB = (u16*)(ws + 134217728 +  6291456);
    u16* WhhF = (u16*)(ws + 134217728 + 12582912);
    u16* WhhB = (u16*)(ws + 134217728 + 18874368);
    u16* Wqkv = (u16*)(ws + 134217728);   // phase B overlay
    u16* WoB  = (u16*)(ws + 134217728);   // phase C overlay
    u16* gi   = (u16*)(ws + 159383552);
    u16* xb   = (u16*)(ws + 159383552 + 50331648);  // shared with gh
    u16* gh   = (u16*)(ws + 159383552 + 50331648);
    u16* qkv  = (u16*)(ws + 159383552);   // phase B overlay
    u16* hWo  = (u16*)(ws + 159383552);   // phase C overlay

    auto cvt = [&](const float* src, u16* dst, long n) {
        long n4 = n >> 2;
        cvt_f32_bf16<<<dim3((unsigned)((n4 + 255) / 256)), dim3(256), 0, stream>>>(src, dst, n4);
    };

    // ---- phase A: bidirectional GRU ----
    cvt(Wihf, WihF, 3072L * 1024);
    cvt(Wihb, WihB, 3072L * 1024);
    cvt(Whhf, WhhF, 3072L * 1024);
    cvt(Whhb, WhhB, 3072L * 1024);

    // forward direction: t = 0,1,2 ; h_t at hs + t*2048 + 0
    for (int t = 0; t < 3; ++t) {
        cvt(xs[t], xb, (long)Bn * In);                                  // xb in gh region (gh dead here)
        gemm_bt<<<dim3(64, 24), dim3(256), 0, stream>>>(xb, 1024, WihF, 1024, gi, 3072, 1024);
        const u16* hprev = nullptr;
        if (t > 0) {
            hprev = hs + (size_t)(t - 1) * 2048;
            gemm_bt<<<dim3(64, 24), dim3(256), 0, stream>>>(hprev, 6144, WhhF, 1024, gh, 3072, 1024);
        }
        gru_pointwise<<<8192, 256, 0, stream>>>(gi, t > 0 ? gh : nullptr, bihf, bhhf,
                                                hprev, hs + (size_t)t * 2048);
    }
    // backward direction: s = 0,1,2 processes t = 2-s ; h at hs + t*2048 + 1024
    for (int s = 0; s < 3; ++s) {
        int t = 2 - s;
        cvt(xs[t], xb, (long)Bn * In);
        gemm_bt<<<dim3(64, 24), dim3(256), 0, stream>>>(xb, 1024, WihB, 1024, gi, 3072, 1024);
        const u16* hprev = nullptr;
        if (s > 0) {
            hprev = hs + (size_t)(t + 1) * 2048 + 1024;
            gemm_bt<<<dim3(64, 24), dim3(256), 0, stream>>>(hprev, 6144, WhhB, 1024, gh, 3072, 1024);
        }
        gru_pointwise<<<8192, 256, 0, stream>>>(gi, s > 0 ? gh : nullptr, bihb, bhhb,
                                                hprev, hs + (size_t)t * 2048 + 1024);
    }

    // ---- phase B: QKV projection + attention, tiled over batch (4 x 2048) ----
    cvt(Wq, Wqkv,                    2048L * 2048);
    cvt(Wk, Wqkv + 2048L * 2048,     2048L * 2048);
    cvt(Wv, Wqkv + 2L * 2048 * 2048, 2048L * 2048);
    for (int i = 0; i < 4; ++i) {
        const u16* hsT = hs + (size_t)i * 6144 * 2048;   // 6144 rows of (24576,2048)
        gemm_bt<<<dim3(48, 48), dim3(256), 0, stream>>>(hsT, 2048, Wqkv, 2048, qkv, 6144, 2048);
        attn_kernel<<<dim3(8192), dim3(256), 0, stream>>>(qkv, csum + (size_t)i * 2048 * 2048);
    }

    // ---- phase C: Wo projection + classifier ----
    cvt(Wo, WoB, 2048L * 2048);
    gemm_bt<<<dim3(64, 16), dim3(256), 0, stream>>>(csum, 2048, WoB, 2048, hWo, 2048, 2048);
    final_kernel<<<dim3(2048), dim3(256), 0, stream>>>(hWo, Wout, bout, out);
}